// Round 5
// baseline (231.065 us; speedup 1.0000x reference)
//
#include <hip/hip_runtime.h>
#include <math.h>

// DivEncoder: x[N,H] -> per-group (D=512 groups, V=16) conv to U=64, ELU,
// conv U->1, row-wise L2 normalize. All fp32 in/out.
#define D_ 512
#define H_ 8192
#define U_ 64
#define V_ 16
#define N_ 4096
#define DUV (D_ * U_ * V_)     // 524288
#define DU  (D_ * U_)          // 32768

#define LOG2E 1.4426950408889634f
#define LN2   0.6931471805599453f

// Block geometry: 64 rows x 8 groups, 256 threads (4 waves).
// Wave w handles groups {2w, 2w+1}, 4 row-tiles of 16 rows each.
#define BR 64
#define BG 8
#define XSTR 136   // bf16 row stride: 272 B (16B-aligned rows, bank rot 4 -> 2-way only)
#define YSTR 12    // f32 row stride: 48 B (16B-aligned), bank rot 12 -> 2-way only

typedef __bf16 bf16x8 __attribute__((ext_vector_type(8)));
typedef __bf16 bf16x4 __attribute__((ext_vector_type(4)));
typedef float f32x4 __attribute__((ext_vector_type(4)));

// ws layout: wh bf16[DUV] @0 | wl bf16[DUV] @1MB | b1s f32[DU] @2MB | w2s f32[DU] @2MB+128KB
#define WS_NEEDED (2 * DUV * sizeof(__bf16) + 2 * DU * sizeof(float))

// Prep A: W1 * log2e -> bf16 hi/lo split (same [d][u][v] layout).
__global__ __launch_bounds__(256) void k0_split_w1(const float* __restrict__ W1,
                                                   __bf16* __restrict__ wh) {
    __bf16* wl = wh + DUV;
    const int i4 = (blockIdx.x * 256 + threadIdx.x) * 4;
    f32x4 w = *(const f32x4*)(W1 + i4);
    bf16x4 h, l;
    #pragma unroll
    for (int j = 0; j < 4; ++j) {
        float wf = w[j] * LOG2E;
        __bf16 hh = (__bf16)wf;
        h[j] = hh;
        l[j] = (__bf16)(wf - (float)hh);
    }
    *(bf16x4*)(wh + i4) = h;
    *(bf16x4*)(wl + i4) = l;
}

// Prep B: b1 * log2e, W2 * ln2 (fp32).
__global__ __launch_bounds__(256) void k0_scale_b1w2(const float* __restrict__ b1,
                                                     const float* __restrict__ W2,
                                                     float* __restrict__ b1s,
                                                     float* __restrict__ w2s) {
    const int i4 = (blockIdx.x * 256 + threadIdx.x) * 4;
    f32x4 b = *(const f32x4*)(b1 + i4);
    f32x4 w = *(const f32x4*)(W2 + i4);
    #pragma unroll
    for (int j = 0; j < 4; ++j) { b[j] *= LOG2E; w[j] *= LN2; }
    *(f32x4*)(b1s + i4) = b;
    *(f32x4*)(w2s + i4) = w;
}

// Split-precision bf16 MFMA (16x16x32): K packs [w_hi | w_lo] (prescaled by
// log2e). MFMA1 B=[x_hi|x_hi], MFMA2 B=[x_lo|x_lo]; sum = log2e*(w.x)+b1'
// exact to ~2^-16 rel, fp32 accum. ELU+conv2 epilogue in exp2 domain:
//   contribution = (w2*ln2) * max(h', (2^min(h',0) - 1)/ln2)  ==  w2 * elu(h)
// Layouts (HW-verified): A/B: idx=lane&15, k=(lane>>4)*8+j ;
// C/D: col=lane&15, row=(lane>>4)*4+reg.
template <bool PRESPLIT>
__global__ __launch_bounds__(256, 4) void k1_div_encoder(
        const float* __restrict__ x,
        const float* __restrict__ W1,
        const __bf16* __restrict__ wsplit,
        const float* __restrict__ b1,
        const float* __restrict__ W2,
        const float* __restrict__ b2,
        float* __restrict__ y) {
    __shared__ __bf16 xhi[BR][XSTR];
    __shared__ __bf16 xlo[BR][XSTR];
    __shared__ float  ytile[BR][YSTR];

    const int tid  = threadIdx.x;
    const int lane = tid & 63;
    const int wave = __builtin_amdgcn_readfirstlane(tid >> 6);
    const int q    = lane >> 4;
    const int m    = lane & 15;
    const int vhalf = (q & 1) * 8;     // which 8 v's this quad holds

    // nb fast: 64 consecutive blocks reuse the same weight slice (L2).
    const int nb = blockIdx.x & 63;    // 64 row-blocks
    const int db = blockIdx.x >> 6;    // 64 group-blocks
    const int r0 = nb * BR;
    const int d0 = db * BG;

    // ---- stage 1: coalesced x load + hi/lo bf16 split -> LDS ----
    {
        const float* xg = x + (size_t)r0 * H_ + (size_t)d0 * V_;
        #pragma unroll
        for (int i = 0; i < 8; ++i) {
            const int flat = tid + i * 256;   // 0..2047
            const int row  = flat >> 5;       // 0..63
            const int c4   = flat & 31;       // f32x4 col
            f32x4 v = *(const f32x4*)(xg + (size_t)row * H_ + c4 * 4);
            bf16x4 h, l;
            #pragma unroll
            for (int j = 0; j < 4; ++j) {
                __bf16 hh = (__bf16)v[j];
                h[j] = hh;
                l[j] = (__bf16)(v[j] - (float)hh);
            }
            *(bf16x4*)&xhi[row][c4 * 4] = h;
            *(bf16x4*)&xlo[row][c4 * 4] = l;
        }
        // zero the ytile accumulator (ds_add target)
        #pragma unroll
        for (int k = tid; k < BR * YSTR; k += 256) {
            ((float*)ytile)[k] = 0.0f;
        }
    }
    __syncthreads();

    #pragma unroll 1
    for (int gi = 0; gi < 2; ++gi) {
        const int gl = wave * 2 + gi;
        const int d  = d0 + gl;

        // A-frags: quads 0,1 = w_hi, quads 2,3 = w_lo (same v's).
        bf16x8 Afrag[4];
        f32x4 b1frag[4], w2frag[4];
        if (PRESPLIT) {
            const __bf16* base = wsplit + (size_t)(q >> 1) * DUV;
            #pragma unroll
            for (int c = 0; c < 4; ++c) {
                Afrag[c] = *(const bf16x8*)(base +
                    ((size_t)d * U_ + c * 16 + m) * V_ + vhalf);
                b1frag[c] = *(const f32x4*)(b1 + (size_t)d * U_ + c * 16 + q * 4);
                w2frag[c] = *(const f32x4*)(W2 + (size_t)d * U_ + c * 16 + q * 4);
            }
        } else {
            #pragma unroll
            for (int c = 0; c < 4; ++c) {
                const float* wp = W1 + ((size_t)d * U_ + c * 16 + m) * V_ + vhalf;
                f32x4 w0 = *(const f32x4*)wp;
                f32x4 w1v = *(const f32x4*)(wp + 4);
                float wf[8] = {w0.x, w0.y, w0.z, w0.w, w1v.x, w1v.y, w1v.z, w1v.w};
                bf16x8 a;
                #pragma unroll
                for (int i = 0; i < 8; ++i) {
                    float ws_ = wf[i] * LOG2E;
                    __bf16 h = (__bf16)ws_;
                    __bf16 lo = (__bf16)(ws_ - (float)h);
                    a[i] = (q < 2) ? h : lo;
                }
                Afrag[c] = a;
                f32x4 bb = *(const f32x4*)(b1 + (size_t)d * U_ + c * 16 + q * 4);
                f32x4 ww = *(const f32x4*)(W2 + (size_t)d * U_ + c * 16 + q * 4);
                #pragma unroll
                for (int j = 0; j < 4; ++j) { bb[j] *= LOG2E; ww[j] *= LN2; }
                b1frag[c] = bb;
                w2frag[c] = ww;
            }
        }

        #pragma unroll 2
        for (int t = 0; t < 4; ++t) {
            bf16x8 bhi = *(const bf16x8*)&xhi[t * 16 + m][gl * V_ + vhalf];
            bf16x8 blo = *(const bf16x8*)&xlo[t * 16 + m][gl * V_ + vhalf];

            float partial = 0.0f;
            #pragma unroll
            for (int c = 0; c < 4; ++c) {
                f32x4 acc = b1frag[c];
                acc = __builtin_amdgcn_mfma_f32_16x16x32_bf16(Afrag[c], bhi, acc, 0, 0, 0);
                acc = __builtin_amdgcn_mfma_f32_16x16x32_bf16(Afrag[c], blo, acc, 0, 0, 0);
                #pragma unroll
                for (int r = 0; r < 4; ++r) {
                    float hp = acc[r];                        // h * log2e
                    float mn = fminf(hp, 0.0f);
                    float t2 = __builtin_amdgcn_exp2f(mn);    // 2^min = e^min(h,0)
                    float e  = fmaf(t2, LOG2E, -LOG2E);       // expm1(h<0)/ln2
                    float vv = fmaxf(hp, e);                  // elu(h)/ln2 in h' units
                    partial  = fmaf(w2frag[c][r], vv, partial);
                }
            }
            // 4 quads hold disjoint u-subsets: accumulate via LDS atomic
            atomicAdd(&ytile[t * 16 + m][gl], partial);
        }
    }
    __syncthreads();

    // ---- stage 3: + b2, coalesced y store ----
    if (tid < 128) {
        const int row  = tid >> 1;
        const int half = tid & 1;
        f32x4 v  = *(const f32x4*)&ytile[row][half * 4];
        f32x4 bb = *(const f32x4*)(b2 + d0 + half * 4);
        #pragma unroll
        for (int j = 0; j < 4; ++j) v[j] += bb[j];
        *(f32x4*)(y + (size_t)(r0 + row) * D_ + d0 + half * 4) = v;
    }
}

// Kernel 2: row-wise L2 normalize in place. One block (256 threads) per row.
__global__ __launch_bounds__(256) void k2_l2_normalize(float* __restrict__ y) {
    const int n = blockIdx.x;
    const int t = threadIdx.x;
    float* row = y + (size_t)n * D_;

    float v0 = row[t];
    float v1 = row[t + 256];
    float ss = v0 * v0 + v1 * v1;

    #pragma unroll
    for (int off = 32; off > 0; off >>= 1) {
        ss += __shfl_down(ss, off, 64);
    }

    __shared__ float wsum[4];
    if ((t & 63) == 0) wsum[t >> 6] = ss;
    __syncthreads();
    const float tot = wsum[0] + wsum[1] + wsum[2] + wsum[3];

    const float scale = 1.0f / fmaxf(sqrtf(tot), 1e-12f);

    row[t]       = v0 * scale;
    row[t + 256] = v1 * scale;
}

extern "C" void kernel_launch(void* const* d_in, const int* in_sizes, int n_in,
                              void* d_out, int out_size, void* d_ws, size_t ws_size,
                              hipStream_t stream) {
    const float* x  = (const float*)d_in[0];
    const float* W1 = (const float*)d_in[1];
    const float* b1 = (const float*)d_in[2];
    const float* W2 = (const float*)d_in[3];
    const float* b2 = (const float*)d_in[4];
    float* y = (float*)d_out;  // [N, D] fp32

    const dim3 grid((N_ / BR) * (D_ / BG));
    if (ws_size >= WS_NEEDED) {
        __bf16* wh  = (__bf16*)d_ws;
        float* b1s  = (float*)((char*)d_ws + 2 * DUV * sizeof(__bf16));
        float* w2s  = b1s + DU;
        k0_split_w1<<<dim3(DUV / 4 / 256), dim3(256), 0, stream>>>(W1, wh);
        k0_scale_b1w2<<<dim3(DU / 4 / 256), dim3(256), 0, stream>>>(b1, W2, b1s, w2s);
        k1_div_encoder<true><<<grid, dim3(256), 0, stream>>>(
            x, W1, wh, b1s, w2s, b2, y);
    } else {
        k1_div_encoder<false><<<grid, dim3(256), 0, stream>>>(
            x, W1, (const __bf16*)nullptr, b1, W2, b2, y);
    }
    k2_l2_normalize<<<dim3(N_), dim3(256), 0, stream>>>(y);
}